// Round 1
// baseline (296.679 us; speedup 1.0000x reference)
//
#include <hip/hip_runtime.h>
#include <hip/hip_bf16.h>

// SpatialBranch: 1088 box-pair indicator maps -> conv1(2->64,5x5)+pool2 ->
// conv2(64->32,5x5)+pool2 -> spatial mean -> FC(32->512)+ReLU, plus slicing.
//
// Strategy:
//  - conv1 collapsed to a per-pair 10x10 window-state table V[c][sy][sx][o]
//    (rect-indicator x 5x5 kernel == rectangular subsum of kernel == SAT diff).
//  - conv1 bias folded into conv2 as constant C2B[oc] (h1 stored WITHOUT b1),
//    so h1 is exactly zero outside box support -> valid conv2 tile skipping.
//  - conv2 as bf16 MFMA implicit GEMM: M=676 positions, N=32 oc, K=1600
//    (taps x 64ic), mfma_f32_32x32x16_bf16, A from swizzled LDS, B from ws.

#define NPAIRS 1088
#define FEAT_SZ (NPAIRS * 512)

typedef __bf16 bf16x8 __attribute__((ext_vector_type(8)));
typedef float f32x16 __attribute__((ext_vector_type(16)));

// workspace layout (bytes)
#define WS_W1SAT 0        // 64*2*36 f32 = 36864  (6x6 SAT per (o,c), zero row/col)
#define WS_C2B 36864      // 32 f32 (conv1-bias folded through conv2)
#define WS_BFRAG 37120    // 100*64*8 bf16 = 102400 (conv2 B-fragments)
// total 139520 bytes of ws

// LDS layout (bytes)
#define SM_H1 0           // h1pool [900][64] bf16 = 115200, XOR-swizzled rows
#define SM_RB 115200      // phase1: V[2][10][10][72] bf16 = 28800 ; phase2: c2 [676][32] bf16 = 43264
#define SM_HM 158464      // h_mean [32] f32
#define SMEM_BYTES 158592

__device__ __forceinline__ unsigned short f2bf(float f) {
  __hip_bfloat16 h = __float2bfloat16(f);
  unsigned short u;
  __builtin_memcpy(&u, &h, 2);
  return u;
}
__device__ __forceinline__ float bflo(unsigned int u) { return __uint_as_float(u << 16); }
__device__ __forceinline__ float bfhi(unsigned int u) { return __uint_as_float(u & 0xffff0000u); }

__device__ __forceinline__ void pair_ij(int k, int* pi, int* pj) {
  int i = 0, rem = k;
  while (rem >= 16 - i) { rem -= 16 - i; ++i; }
  *pi = i;
  *pj = i + 1 + rem;
}

// window state for coordinate z vs interval [a,b): 0 empty, 1..4 left-partial
// (k0=s,k1=5), 5 full, 6..9 right-partial (k0=0,k1=s-5). Valid since b-a>=4.
__device__ __forceinline__ int stz(int z, int a, int b) {
  if (z >= a) {
    if (z >= b) return 0;
    if (z <= b - 5) return 5;
    return 5 + (b - z);
  }
  if (z >= a - 4) return a - z;
  return 0;
}

__global__ void prep_kernel(const float* __restrict__ w1, const float* __restrict__ b1,
                            const float* __restrict__ w2, float* __restrict__ out,
                            unsigned char* __restrict__ ws) {
  int tid = blockIdx.x * blockDim.x + threadIdx.x;
  float* w1sat = (float*)(ws + WS_W1SAT);
  float* c2b = (float*)(ws + WS_C2B);
  unsigned short* bfrag = (unsigned short*)(ws + WS_BFRAG);

  if (tid < 128) {
    // 6x6 prefix-sum (SAT) of w1[o][c], S[0][*]=S[*][0]=0
    int o = tid >> 1, c = tid & 1;
    const float* w = w1 + (o * 2 + c) * 25;
    float* S = w1sat + (o * 2 + c) * 36;
    for (int j = 0; j < 6; ++j) S[j] = 0.f;
    for (int iy = 1; iy <= 5; ++iy) {
      S[iy * 6] = 0.f;
      float rp = 0.f;
      for (int j = 1; j <= 5; ++j) {
        rp += w[(iy - 1) * 5 + (j - 1)];
        S[iy * 6 + j] = S[(iy - 1) * 6 + j] + rp;
      }
    }
  } else if (tid < 160) {
    // C2B[oc] = sum_ic b1[ic] * sum_tap w2[oc][ic][tap]
    int oc = tid - 128;
    float s = 0.f;
    for (int ic = 0; ic < 64; ++ic) {
      const float* wp = w2 + (oc * 64 + ic) * 25;
      float t = 0.f;
      for (int q = 0; q < 25; ++q) t += wp[q];
      s += b1[ic] * t;
    }
    c2b[oc] = s;
  } else if (tid < 160 + NPAIRS) {
    // slicing output (as float values; d_out read back as float32)
    int p = tid - 160;
    int b = p / 136, k = p % 136, i, j;
    pair_ij(k, &i, &j);
    out[FEAT_SZ + p * 3 + 0] = (float)b;
    out[FEAT_SZ + p * 3 + 1] = (float)i;
    out[FEAT_SZ + p * 3 + 2] = (float)j;
  } else if (tid >= 1248 && tid < 1248 + 6400) {
    // conv2 B fragments: B[k][n], k = s*16 + (lane>>5)*8 + i, n = lane&31
    // K order: kk = tap*64 + ic
    int idx = tid - 1248;
    int s = idx >> 6, lane = idx & 63;
    int tap = s >> 2, icb = (s & 3) * 16;
    int ky = tap / 5, kx = tap - ky * 5;
    int n = lane & 31, hi = lane >> 5;
    unsigned short* dst = bfrag + (s * 64 + lane) * 8;
    for (int i2 = 0; i2 < 8; ++i2) {
      int ic = icb + hi * 8 + i2;
      dst[i2] = f2bf(w2[(n * 64 + ic) * 25 + ky * 5 + kx]);
    }
  }
}

__global__ __launch_bounds__(512) void main_kernel(
    const float* __restrict__ bboxes, const float* __restrict__ b2,
    const float* __restrict__ fcw, const float* __restrict__ fcb,
    const unsigned char* __restrict__ ws, float* __restrict__ out) {
  __shared__ __align__(16) unsigned char smem[SMEM_BYTES];
  const int tid = threadIdx.x;
  const int lane = tid & 63;
  const int wid = tid >> 6;
  const int p = blockIdx.x;

  // ---- pair constants (uniform) ----
  int b = p / 136, k = p % 136, bi, bj;
  pair_ij(k, &bi, &bj);
  const float* bbA = bboxes + (b * 17 + bi) * 4;
  const float* bbB = bboxes + (b * 17 + bj) * 4;
  int ax[2], ay[2], bx[2], by[2];
  {
    auto cl = [](float v) { int t = (int)ceilf(v); return t < 0 ? 0 : (t > 64 ? 64 : t); };
    ax[0] = cl(bbA[0]); ay[0] = cl(bbA[1]); bx[0] = cl(bbA[2]); by[0] = cl(bbA[3]);
    ax[1] = cl(bbB[0]); ay[1] = cl(bbB[1]); bx[1] = cl(bbB[2]); by[1] = cl(bbB[3]);
  }

  // ---- phase 0: zero h1, build V table ----
  for (int idx = tid; idx < 7200; idx += 512)  // 115200 B of h1
    ((uint4*)smem)[idx] = make_uint4(0, 0, 0, 0);

  {
    const float* w1sat = (const float*)(ws + WS_W1SAT);
    unsigned short* V = (unsigned short*)(smem + SM_RB);
    for (int e = tid; e < 12800; e += 512) {
      int o = e & 63;
      int q = e >> 6;
      int sx = q % 10; q /= 10;
      int sy = q % 10;
      int c = q / 10;
      int ky0 = (sy <= 4) ? sy : 0;
      int ky1 = (sy == 0) ? 0 : ((sy <= 5) ? 5 : sy - 5);
      int kx0 = (sx <= 4) ? sx : 0;
      int kx1 = (sx == 0) ? 0 : ((sx <= 5) ? 5 : sx - 5);
      const float* S = w1sat + (o * 2 + c) * 36;
      float v = S[ky1 * 6 + kx1] - S[ky0 * 6 + kx1] - S[ky1 * 6 + kx0] + S[ky0 * 6 + kx0];
      V[(c * 100 + sy * 10 + sx) * 72 + o] = f2bf(v);  // row padded to 72 elems
    }
  }
  __syncthreads();

  // ---- phase 1: conv1 + pool1 via V lookups; h1 stored WITHOUT b1 ----
  {
    const unsigned char* Vb = smem + SM_RB;
    for (int pos = tid; pos < 900; pos += 512) {
      int py = pos / 30, px = pos - py * 30;
      int oy = py * 2, ox = px * 2;
      int sy[2][2], sx[2][2];
#pragma unroll
      for (int c = 0; c < 2; ++c) {
        sy[c][0] = stz(oy, ay[c], by[c]);
        sy[c][1] = stz(oy + 1, ay[c], by[c]);
        sx[c][0] = stz(ox, ax[c], bx[c]);
        sx[c][1] = stz(ox + 1, ax[c], bx[c]);
      }
      bool e0 = ((sy[0][0] | sy[0][1]) == 0) || ((sx[0][0] | sx[0][1]) == 0);
      bool e1 = ((sy[1][0] | sy[1][1]) == 0) || ((sx[1][0] | sx[1][1]) == 0);
      if (e0 && e1) continue;  // h1 row already zeroed

      unsigned ro[2][4];
#pragma unroll
      for (int c = 0; c < 2; ++c)
#pragma unroll
        for (int dy = 0; dy < 2; ++dy)
#pragma unroll
          for (int dx = 0; dx < 2; ++dx)
            ro[c][dy * 2 + dx] = (unsigned)((c * 100 + sy[c][dy] * 10 + sx[c][dx]) * 144);

      unsigned hbase = (unsigned)pos * 128u;
      unsigned swz = ((unsigned)pos & 7u) << 4;
#pragma unroll
      for (int ch = 0; ch < 8; ++ch) {
        unsigned cb = (unsigned)ch * 16u;
        float mxl[4], mxh[4];
#pragma unroll
        for (int sp = 0; sp < 4; ++sp) {
          uint4 u0 = *(const uint4*)(Vb + ro[0][sp] + cb);
          uint4 u1 = *(const uint4*)(Vb + ro[1][sp] + cb);
          unsigned a0[4] = {u0.x, u0.y, u0.z, u0.w};
          unsigned a1[4] = {u1.x, u1.y, u1.z, u1.w};
#pragma unroll
          for (int d = 0; d < 4; ++d) {
            float vl = bflo(a0[d]) + bflo(a1[d]);
            float vh = bfhi(a0[d]) + bfhi(a1[d]);
            if (sp == 0) { mxl[d] = vl; mxh[d] = vh; }
            else { mxl[d] = fmaxf(mxl[d], vl); mxh[d] = fmaxf(mxh[d], vh); }
          }
        }
        unsigned od[4];
#pragma unroll
        for (int d = 0; d < 4; ++d)
          od[d] = (unsigned)f2bf(mxl[d]) | ((unsigned)f2bf(mxh[d]) << 16);
        uint4 ov; ov.x = od[0]; ov.y = od[1]; ov.z = od[2]; ov.w = od[3];
        *(uint4*)(smem + hbase + (cb ^ swz)) = ov;  // swizzled h1 row
      }
    }
  }
  __syncthreads();

  // ---- phase 2: conv2 as MFMA implicit GEMM ----
  const int oc = lane & 31;
  const float c2bb = ((const float*)(ws + WS_C2B))[oc] + b2[oc];
  unsigned short* c2 = (unsigned short*)(smem + SM_RB);
  {
    unsigned short cu = f2bf(c2bb);
    for (int idx = tid; idx < 21632; idx += 512) c2[idx] = cu;  // idx&31 == tid&31 == oc
  }

  // active conv2 output row range (h1 zero outside support; bias folded -> valid skip)
  int s0a = ay[0] - 4 < 0 ? 0 : ay[0] - 4;
  int s0b = ay[1] - 4 < 0 ? 0 : ay[1] - 4;
  int pre0 = s0a < s0b ? s0a : s0b;
  int e0a = by[0] < 60 ? by[0] : 60;
  int e0b = by[1] < 60 ? by[1] : 60;
  int pre1 = e0a > e0b ? e0a : e0b;
  int pr0 = pre0 >> 1, pr1 = (pre1 - 1) >> 1;
  int or0 = pr0 - 4 < 0 ? 0 : pr0 - 4;
  int or1 = pr1 > 25 ? 25 : pr1;
  int poslo = or0 * 26, poshi = (or1 + 1) * 26;

  int tb[3]; bool act[3]; int ppb[3]; bool anyact = false;
#pragma unroll
  for (int ti = 0; ti < 3; ++ti) {
    int t = wid + ti * 8;
    tb[ti] = t * 32;
    bool a = (t < 22) && (tb[ti] < poshi) && (tb[ti] + 32 > poslo);
    act[ti] = a; anyact |= a;
    int pos = tb[ti] + (lane & 31);
    if (pos > 675) pos = 675;
    int oy2 = pos / 26, ox2 = pos - oy2 * 26;
    ppb[ti] = oy2 * 30 + ox2;
  }

  f32x16 acc[3];
#pragma unroll
  for (int ti = 0; ti < 3; ++ti)
#pragma unroll
    for (int r = 0; r < 16; ++r) acc[ti][r] = 0.f;

  if (anyact) {
    const uint4* bfragp = (const uint4*)(ws + WS_BFRAG);
    const unsigned hv = ((unsigned)(lane >> 5)) * 16u;
#pragma unroll 4
    for (int s = 0; s < 100; ++s) {
      uint4 bq = bfragp[s * 64 + lane];
      bf16x8 bop = __builtin_bit_cast(bf16x8, bq);
      int tap = s >> 2;
      int ky = tap / 5, kx = tap - ky * 5;
      int dtap = ky * 30 + kx;
      unsigned t1 = (unsigned)(s & 3) * 32u + hv;
#pragma unroll
      for (int ti = 0; ti < 3; ++ti) {
        if (!act[ti]) continue;
        unsigned pp = (unsigned)(ppb[ti] + dtap);
        unsigned addr = pp * 128u + (t1 ^ ((pp & 7u) << 4));
        uint4 aq = *(const uint4*)(smem + addr);
        bf16x8 aop = __builtin_bit_cast(bf16x8, aq);
        acc[ti] = __builtin_amdgcn_mfma_f32_32x32x16_bf16(aop, bop, acc[ti], 0, 0, 0);
      }
    }
  }
  __syncthreads();  // c2 init complete everywhere; now write tiles

#pragma unroll
  for (int ti = 0; ti < 3; ++ti) {
    if (!act[ti]) continue;
#pragma unroll
    for (int r = 0; r < 16; ++r) {
      int row = (r & 3) + 8 * (r >> 2) + 4 * (lane >> 5);
      int pos = tb[ti] + row;
      if (pos < 676) c2[pos * 32 + oc] = f2bf(acc[ti][r] + c2bb);
    }
  }
  __syncthreads();

  // ---- phase 3: pool2 + spatial mean ----
  {
    float* hm = (float*)(smem + SM_HM);
    int moc = tid >> 4;
    int mi = tid & 15;
    float ssum = 0.f;
    for (int q = mi; q < 169; q += 16) {
      int py = q / 13, px = q - py * 13;
      int p0 = (py * 2) * 26 + px * 2;
      float v00 = bflo(c2[p0 * 32 + moc]);
      float v01 = bflo(c2[(p0 + 1) * 32 + moc]);
      float v10 = bflo(c2[(p0 + 26) * 32 + moc]);
      float v11 = bflo(c2[(p0 + 27) * 32 + moc]);
      ssum += fmaxf(fmaxf(v00, v01), fmaxf(v10, v11));
    }
    ssum += __shfl_xor(ssum, 1);
    ssum += __shfl_xor(ssum, 2);
    ssum += __shfl_xor(ssum, 4);
    ssum += __shfl_xor(ssum, 8);
    if (mi == 0) hm[moc] = ssum * (1.0f / 169.0f);
  }
  __syncthreads();

  // ---- phase 4: FC + ReLU ----
  {
    const float* hm = (const float*)(smem + SM_HM);
    float a = fcb[tid];
    const float* wrow = fcw + tid * 32;
#pragma unroll 8
    for (int o2 = 0; o2 < 32; ++o2) a = fmaf(hm[o2], wrow[o2], a);
    out[p * 512 + tid] = fmaxf(a, 0.f);
  }
}

extern "C" void kernel_launch(void* const* d_in, const int* in_sizes, int n_in,
                              void* d_out, int out_size, void* d_ws, size_t ws_size,
                              hipStream_t stream) {
  const float* bboxes = (const float*)d_in[0];
  const float* w1 = (const float*)d_in[1];
  const float* b1 = (const float*)d_in[2];
  const float* w2 = (const float*)d_in[3];
  const float* b2 = (const float*)d_in[4];
  const float* fcw = (const float*)d_in[5];
  const float* fcb = (const float*)d_in[6];
  float* out = (float*)d_out;
  unsigned char* ws = (unsigned char*)d_ws;

  hipLaunchKernelGGL(prep_kernel, dim3(32), dim3(256), 0, stream, w1, b1, w2, out, ws);
  hipLaunchKernelGGL(main_kernel, dim3(NPAIRS), dim3(512), 0, stream, bboxes, b2, fcw, fcb, ws, out);
}

// Round 2
// 128.723 us; speedup vs baseline: 2.3048x; 2.3048x over previous
//
#include <hip/hip_runtime.h>
#include <hip/hip_bf16.h>

// SpatialBranch: 1088 box-pair indicator maps -> conv1(2->64,5x5)+pool2 ->
// conv2(64->32,5x5)+pool2 -> spatial mean -> FC(32->512)+ReLU, plus slicing.
//
// Round 2 changes (latency/occupancy-bound per rocprof: Occ 19.9%, MfmaUtil 7.9%):
//  - h1 stored as fp8 e4m3 in LDS (57.6 KB), conv2 via mfma_f32_32x32x16_fp8_fp8.
//  - V window-table is pair-INDEPENDENT -> built once in prep, read from L2.
//  - c2 aliases h1's LDS region after the MFMA loop (no prefill; inactive tiles
//    write bias directly). LDS 158.7 KB -> 59.8 KB => 2 blocks/CU, 4 waves/SIMD.
//  - 8B-granular XOR swizzle on h1 rows: slot ^ (pos&7) ^ ((pos>>1)&4) -> 2-way.

#define NPAIRS 1088
#define FEAT_SZ (NPAIRS * 512)

typedef float f32x16 __attribute__((ext_vector_type(16)));

// workspace layout (bytes)
#define WS_V 0            // V[2][10][10][64] bf16 = 25600 (pair-independent conv1 window table)
#define WS_C2B 25600      // 32 f32 (conv1-bias folded through conv2)
#define WS_BFRAG 25728    // 100*64*8 fp8 = 51200 (conv2 B-fragments)
// total 76928 bytes of ws

// LDS layout (bytes)
#define SM_H1 0           // phase<=2: h1pool [900][64] fp8 = 57600, swizzled rows
                          // phase>=3: c2 [676][32] bf16 = 43264 (aliases h1)
#define SM_HM 57600       // h_mean [32] f32
#define SM_PART 57728     // partial [16][32] f32 = 2048
#define SMEM_BYTES 59776

__device__ __forceinline__ unsigned short f2bf(float f) {
  __hip_bfloat16 h = __float2bfloat16(f);
  unsigned short u;
  __builtin_memcpy(&u, &h, 2);
  return u;
}
__device__ __forceinline__ float bflo(unsigned int u) { return __uint_as_float(u << 16); }
__device__ __forceinline__ float bfhi(unsigned int u) { return __uint_as_float(u & 0xffff0000u); }

__device__ __forceinline__ void pair_ij(int k, int* pi, int* pj) {
  int i = 0, rem = k;
  while (rem >= 16 - i) { rem -= 16 - i; ++i; }
  *pi = i;
  *pj = i + 1 + rem;
}

// window state for coordinate z vs interval [a,b): 0 empty, 1..4 left-partial
// (k0=s,k1=5), 5 full, 6..9 right-partial (k0=0,k1=s-5). Valid since b-a>=4.
__device__ __forceinline__ int stz(int z, int a, int b) {
  if (z >= a) {
    if (z >= b) return 0;
    if (z <= b - 5) return 5;
    return 5 + (b - z);
  }
  if (z >= a - 4) return a - z;
  return 0;
}

// swizzled byte offset of 8B slot within a 64B h1 row
__device__ __forceinline__ unsigned swz8(unsigned pos, unsigned slot) {
  return (slot ^ (pos & 7u) ^ ((pos >> 1) & 4u)) << 3;
}

__global__ void prep_kernel(const float* __restrict__ w1, const float* __restrict__ b1,
                            const float* __restrict__ w2, float* __restrict__ out,
                            unsigned char* __restrict__ ws) {
  int tid = blockIdx.x * blockDim.x + threadIdx.x;

  if (tid < 12800) {
    // V[c][sy][sx][o]: conv1 response of window-state (sy,sx) = rect subsum of w1[o][c]
    int o = tid & 63;
    int q = tid >> 6;
    int sx = q % 10; q /= 10;
    int sy = q % 10;
    int c = q / 10;
    int ky0 = (sy <= 4) ? sy : 0;
    int ky1 = (sy == 0) ? 0 : ((sy <= 5) ? 5 : sy - 5);
    int kx0 = (sx <= 4) ? sx : 0;
    int kx1 = (sx == 0) ? 0 : ((sx <= 5) ? 5 : sx - 5);
    const float* w = w1 + (o * 2 + c) * 25;
    float v = 0.f;
    for (int ky = ky0; ky < ky1; ++ky)
      for (int kx = kx0; kx < kx1; ++kx) v += w[ky * 5 + kx];
    ((unsigned short*)(ws + WS_V))[(c * 100 + sy * 10 + sx) * 64 + o] = f2bf(v);
  } else if (tid < 12832) {
    // C2B[oc] = sum_ic b1[ic] * sum_tap w2[oc][ic][tap]
    int oc = tid - 12800;
    float s = 0.f;
    for (int ic = 0; ic < 64; ++ic) {
      const float* wp = w2 + (oc * 64 + ic) * 25;
      float t = 0.f;
      for (int q2 = 0; q2 < 25; ++q2) t += wp[q2];
      s += b1[ic] * t;
    }
    ((float*)(ws + WS_C2B))[oc] = s;
  } else if (tid < 13920) {
    // slicing output (as float values; d_out read back as float32)
    int p = tid - 12832;
    int b = p / 136, k = p % 136, i, j;
    pair_ij(k, &i, &j);
    out[FEAT_SZ + p * 3 + 0] = (float)b;
    out[FEAT_SZ + p * 3 + 1] = (float)i;
    out[FEAT_SZ + p * 3 + 2] = (float)j;
  } else if (tid < 20320) {
    // conv2 B fragments (fp8): B[k][n], k=(lane>>5)*8+i within s-step, n=lane&31
    // K order: kk = tap*64 + ic ; s = tap*4 + icblock
    int idx = tid - 13920;
    int s = idx >> 6, lane = idx & 63;
    int tap = s >> 2, icb = (s & 3) * 16;
    int n = lane & 31, hi = lane >> 5;
    float v[8];
    for (int i2 = 0; i2 < 8; ++i2) {
      int ic = icb + hi * 8 + i2;
      v[i2] = w2[(n * 64 + ic) * 25 + tap];
    }
    unsigned q0 = 0, q1 = 0;
    q0 = __builtin_amdgcn_cvt_pk_fp8_f32(v[0], v[1], q0, false);
    q0 = __builtin_amdgcn_cvt_pk_fp8_f32(v[2], v[3], q0, true);
    q1 = __builtin_amdgcn_cvt_pk_fp8_f32(v[4], v[5], q1, false);
    q1 = __builtin_amdgcn_cvt_pk_fp8_f32(v[6], v[7], q1, true);
    ((uint2*)(ws + WS_BFRAG))[s * 64 + lane] = make_uint2(q0, q1);
  }
}

__global__ __launch_bounds__(512, 4) void main_kernel(
    const float* __restrict__ bboxes, const float* __restrict__ b2,
    const float* __restrict__ fcw, const float* __restrict__ fcb,
    const unsigned char* __restrict__ ws, float* __restrict__ out) {
  __shared__ __align__(16) unsigned char smem[SMEM_BYTES];
  const int tid = threadIdx.x;
  const int lane = tid & 63;
  const int wid = tid >> 6;
  const int p = blockIdx.x;

  // ---- pair constants (uniform) ----
  int b = p / 136, k = p % 136, bi, bj;
  pair_ij(k, &bi, &bj);
  const float* bbA = bboxes + (b * 17 + bi) * 4;
  const float* bbB = bboxes + (b * 17 + bj) * 4;
  int ax[2], ay[2], bx[2], by[2];
  {
    auto cl = [](float v) { int t = (int)ceilf(v); return t < 0 ? 0 : (t > 64 ? 64 : t); };
    ax[0] = cl(bbA[0]); ay[0] = cl(bbA[1]); bx[0] = cl(bbA[2]); by[0] = cl(bbA[3]);
    ax[1] = cl(bbB[0]); ay[1] = cl(bbB[1]); bx[1] = cl(bbB[2]); by[1] = cl(bbB[3]);
  }

  // ---- phase 0: zero h1 (fp8, 57600 B) ----
  for (int idx = tid; idx < 3600; idx += 512)
    ((uint4*)smem)[idx] = make_uint4(0, 0, 0, 0);
  __syncthreads();

  // ---- phase 1: conv1 + pool1 via V lookups (from L2); h1 fp8, WITHOUT b1 ----
  {
    const unsigned short* Vg = (const unsigned short*)(ws + WS_V);
    for (int pos = tid; pos < 900; pos += 512) {
      int py = pos / 30, px = pos - py * 30;
      int oy = py * 2, ox = px * 2;
      int sy[2][2], sx[2][2];
#pragma unroll
      for (int c = 0; c < 2; ++c) {
        sy[c][0] = stz(oy, ay[c], by[c]);
        sy[c][1] = stz(oy + 1, ay[c], by[c]);
        sx[c][0] = stz(ox, ax[c], bx[c]);
        sx[c][1] = stz(ox + 1, ax[c], bx[c]);
      }
      bool e0 = ((sy[0][0] | sy[0][1]) == 0) || ((sx[0][0] | sx[0][1]) == 0);
      bool e1 = ((sy[1][0] | sy[1][1]) == 0) || ((sx[1][0] | sx[1][1]) == 0);
      if (e0 && e1) continue;  // h1 row already zeroed

      const uint4* r0[4];
      const uint4* r1[4];
#pragma unroll
      for (int dy = 0; dy < 2; ++dy)
#pragma unroll
        for (int dx = 0; dx < 2; ++dx) {
          r0[dy * 2 + dx] = (const uint4*)(Vg + (0 * 100 + sy[0][dy] * 10 + sx[0][dx]) * 64);
          r1[dy * 2 + dx] = (const uint4*)(Vg + (1 * 100 + sy[1][dy] * 10 + sx[1][dx]) * 64);
        }

      unsigned swzm = ((unsigned)pos & 7u) ^ (((unsigned)pos >> 1) & 4u);
      unsigned hbase = (unsigned)pos * 64u;
#pragma unroll
      for (int g = 0; g < 8; ++g) {  // 8 channels per group
        float mx[8];
#pragma unroll
        for (int sp = 0; sp < 4; ++sp) {
          uint4 u0 = r0[sp][g];
          uint4 u1 = r1[sp][g];
          unsigned a0[4] = {u0.x, u0.y, u0.z, u0.w};
          unsigned a1[4] = {u1.x, u1.y, u1.z, u1.w};
#pragma unroll
          for (int d = 0; d < 4; ++d) {
            float vl = bflo(a0[d]) + bflo(a1[d]);
            float vh = bfhi(a0[d]) + bfhi(a1[d]);
            if (sp == 0) { mx[2 * d] = vl; mx[2 * d + 1] = vh; }
            else { mx[2 * d] = fmaxf(mx[2 * d], vl); mx[2 * d + 1] = fmaxf(mx[2 * d + 1], vh); }
          }
        }
        unsigned q0 = 0, q1 = 0;
        q0 = __builtin_amdgcn_cvt_pk_fp8_f32(mx[0], mx[1], q0, false);
        q0 = __builtin_amdgcn_cvt_pk_fp8_f32(mx[2], mx[3], q0, true);
        q1 = __builtin_amdgcn_cvt_pk_fp8_f32(mx[4], mx[5], q1, false);
        q1 = __builtin_amdgcn_cvt_pk_fp8_f32(mx[6], mx[7], q1, true);
        *(uint2*)(smem + hbase + swz8(pos, (unsigned)g)) = make_uint2(q0, q1);
      }
    }
  }
  __syncthreads();

  // ---- phase 2: conv2 as fp8 MFMA implicit GEMM ----
  const int oc = lane & 31;
  const float c2bb = ((const float*)(ws + WS_C2B))[oc] + b2[oc];

  // active conv2 output row range (h1 zero outside support; bias folded -> valid skip)
  int s0a = ay[0] - 4 < 0 ? 0 : ay[0] - 4;
  int s0b = ay[1] - 4 < 0 ? 0 : ay[1] - 4;
  int pre0 = s0a < s0b ? s0a : s0b;
  int e0a = by[0] < 60 ? by[0] : 60;
  int e0b = by[1] < 60 ? by[1] : 60;
  int pre1 = e0a > e0b ? e0a : e0b;
  int pr0 = pre0 >> 1, pr1 = (pre1 - 1) >> 1;
  int or0 = pr0 - 4 < 0 ? 0 : pr0 - 4;
  int or1 = pr1 > 25 ? 25 : pr1;
  int poslo = or0 * 26, poshi = (or1 + 1) * 26;

  int tb[3]; bool act[3]; int ppb[3]; bool anyact = false;
#pragma unroll
  for (int ti = 0; ti < 3; ++ti) {
    int t = wid + ti * 8;
    tb[ti] = t * 32;
    bool a = (t < 22) && (tb[ti] < poshi) && (tb[ti] + 32 > poslo);
    act[ti] = a; anyact |= a;
    int pos = tb[ti] + (lane & 31);
    if (pos > 675) pos = 675;
    int oy2 = pos / 26, ox2 = pos - oy2 * 26;
    ppb[ti] = oy2 * 30 + ox2;
  }

  f32x16 acc[3];
#pragma unroll
  for (int ti = 0; ti < 3; ++ti)
#pragma unroll
    for (int r = 0; r < 16; ++r) acc[ti][r] = 0.f;

  if (anyact) {
    const uint2* bfragp = (const uint2*)(ws + WS_BFRAG);
    const unsigned hv = (unsigned)(lane >> 5);
#pragma unroll 4
    for (int s = 0; s < 100; ++s) {
      uint2 bq = bfragp[s * 64 + lane];
      long long bop = __builtin_bit_cast(long long, bq);
      int tap = s >> 2;
      int ky = tap / 5, kx = tap - ky * 5;
      int dtap = ky * 30 + kx;
      unsigned slot = (unsigned)(s & 3) * 2u + hv;
#pragma unroll
      for (int ti = 0; ti < 3; ++ti) {
        if (!act[ti]) continue;
        unsigned pp = (unsigned)(ppb[ti] + dtap);
        uint2 aq = *(const uint2*)(smem + pp * 64u + swz8(pp, slot));
        long long aop = __builtin_bit_cast(long long, aq);
        acc[ti] = __builtin_amdgcn_mfma_f32_32x32x16_fp8_fp8(aop, bop, acc[ti], 0, 0, 0);
      }
    }
  }
  __syncthreads();  // all h1 reads done; c2 may now overwrite h1's LDS region

  // every tile writes (inactive tiles have acc==0 -> bias value), covering all 676
  unsigned short* c2 = (unsigned short*)smem;
#pragma unroll
  for (int ti = 0; ti < 3; ++ti) {
#pragma unroll
    for (int r = 0; r < 16; ++r) {
      int row = (r & 3) + 8 * (r >> 2) + 4 * (lane >> 5);
      int pos = tb[ti] + row;
      if (pos < 676) c2[pos * 32 + oc] = f2bf(acc[ti][r] + c2bb);
    }
  }
  __syncthreads();

  // ---- phase 3: pool2 + spatial mean (lanes 0..31 -> consecutive oc, conflict-free) ----
  {
    float* partial = (float*)(smem + SM_PART);
    int moc = lane & 31;
    int mi = wid * 2 + (lane >> 5);  // 0..15
    float ssum = 0.f;
    for (int q = mi; q < 169; q += 16) {
      int py = q / 13, px = q - py * 13;
      int p0 = (py * 2) * 26 + px * 2;
      float v00 = bflo(c2[p0 * 32 + moc]);
      float v01 = bflo(c2[(p0 + 1) * 32 + moc]);
      float v10 = bflo(c2[(p0 + 26) * 32 + moc]);
      float v11 = bflo(c2[(p0 + 27) * 32 + moc]);
      ssum += fmaxf(fmaxf(v00, v01), fmaxf(v10, v11));
    }
    partial[mi * 32 + moc] = ssum;
  }
  __syncthreads();
  if (tid < 32) {
    const float* partial = (const float*)(smem + SM_PART);
    float s = 0.f;
#pragma unroll
    for (int mi = 0; mi < 16; ++mi) s += partial[mi * 32 + tid];
    ((float*)(smem + SM_HM))[tid] = s * (1.0f / 169.0f);
  }
  __syncthreads();

  // ---- phase 4: FC + ReLU ----
  {
    const float* hm = (const float*)(smem + SM_HM);
    float a = fcb[tid];
    const float* wrow = fcw + tid * 32;
#pragma unroll 8
    for (int o2 = 0; o2 < 32; ++o2) a = fmaf(hm[o2], wrow[o2], a);
    out[p * 512 + tid] = fmaxf(a, 0.f);
  }
}

extern "C" void kernel_launch(void* const* d_in, const int* in_sizes, int n_in,
                              void* d_out, int out_size, void* d_ws, size_t ws_size,
                              hipStream_t stream) {
  const float* bboxes = (const float*)d_in[0];
  const float* w1 = (const float*)d_in[1];
  const float* b1 = (const float*)d_in[2];
  const float* w2 = (const float*)d_in[3];
  const float* b2 = (const float*)d_in[4];
  const float* fcw = (const float*)d_in[5];
  const float* fcb = (const float*)d_in[6];
  float* out = (float*)d_out;
  unsigned char* ws = (unsigned char*)d_ws;

  hipLaunchKernelGGL(prep_kernel, dim3(80), dim3(256), 0, stream, w1, b1, w2, out, ws);
  hipLaunchKernelGGL(main_kernel, dim3(NPAIRS), dim3(512), 0, stream, bboxes, b2, fcw, fcb, ws, out);
}